// Round 3
// baseline (17932.465 us; speedup 1.0000x reference)
//
#include <hip/hip_runtime.h>
#include <hip/hip_bf16.h>
#include <hip/hip_fp16.h>
#include <stdint.h>
#include <type_traits>

// Problem constants
#define B_ 64
#define T_ 1024
#define I_ 256
#define H_ 512
#define G3_ 1536
#define O_ 256

typedef __attribute__((ext_vector_type(4))) float floatx4;
typedef __attribute__((ext_vector_type(8))) short short8;
typedef __attribute__((ext_vector_type(2))) _Float16 half2v;

// Raw workgroup barrier: drains LDS only, NOT vmcnt. Keeps HBM/LLC ops
// (out stores, xg prefetch) off the per-step critical path.
#define BARX() __asm__ volatile("s_waitcnt lgkmcnt(0)\n\ts_barrier" ::: "memory")

static __device__ __forceinline__ float fdot2f(uint32_t a, uint32_t b, float c) {
#if __has_builtin(__builtin_amdgcn_fdot2)
  return __builtin_amdgcn_fdot2(__builtin_bit_cast(half2v, a),
                                __builtin_bit_cast(half2v, b), c, false);
#else
  __half2 ha = __builtin_bit_cast(__half2, a);
  __half2 hb = __builtin_bit_cast(__half2, b);
  float2 fa = __half22float2(ha), fb = __half22float2(hb);
  return c + fa.x * fb.x + fa.y * fb.y;
#endif
}

static __device__ __forceinline__ float sigmoid_f(float x) {
  float e = __expf(-fabsf(x));
  float a = 1.f / (1.f + e);
  return x >= 0.f ? a : 1.f - a;
}
static __device__ __forceinline__ float tanh_f(float x) {
  float e = __expf(-2.f * fabsf(x));
  float a = (1.f - e) / (1.f + e);
  return x >= 0.f ? a : -a;
}
static __device__ __forceinline__ uint32_t pack_h2(float a, float b) {
  return (uint32_t)__half_as_ushort(__float2half(a)) |
         ((uint32_t)__half_as_ushort(__float2half(b)) << 16);
}
static __device__ __forceinline__ uint32_t pack_bf2(float a, float b) {
  return (uint32_t)__builtin_bit_cast(unsigned short, __float2bfloat16(a)) |
         ((uint32_t)__builtin_bit_cast(unsigned short, __float2bfloat16(b)) << 16);
}

// ---------------------------------------------------------------------------
// init: pack W_hh -> fp16 register layout, combined biases, zero tags/hstate
// wpack dword index: j + 128*g + 384*kk + 24576*s + 98304*c + 393216*l
// ---------------------------------------------------------------------------
__global__ void init_kernel(const float* __restrict__ Whh0, const float* __restrict__ Whh1,
                            const float* __restrict__ bih0, const float* __restrict__ bhh0,
                            const float* __restrict__ bih1, const float* __restrict__ bhh1,
                            uint32_t* __restrict__ wpack, float* __restrict__ biasv,
                            uint32_t* __restrict__ tags, uint32_t* __restrict__ hstate) {
  int idx = blockIdx.x * 256 + threadIdx.x;
  if (idx < 786432) {
    int l = idx / 393216, rem = idx % 393216;
    int j = rem & 127;
    int g = (rem >> 7) % 3;
    int kk = (rem / 384) & 63;
    int s = (rem / 24576) & 3;
    int c = rem / 98304;
    const float* W = l ? Whh1 : Whh0;
    int row = g * 512 + c * 128 + j;
    int k = s * 128 + kk * 2;
    uint32_t lo = __half_as_ushort(__float2half(W[(size_t)row * 512 + k]));
    uint32_t hi = __half_as_ushort(__float2half(W[(size_t)row * 512 + k + 1]));
    wpack[idx] = lo | (hi << 16);
  }
  int i2 = idx - 786432;
  if (i2 >= 0 && i2 < 3072) {
    int l = i2 / 1536, n = i2 % 1536;
    const float* bi = l ? bih1 : bih0;
    const float* bh = l ? bhh1 : bhh0;
    biasv[i2] = bi[n] + (n < 1024 ? bh[n] : 0.f);
  }
  int i3 = idx - (786432 + 3072);
  if (i3 >= 0 && i3 < 8192) tags[i3] = 0u;
  int i4 = idx - (786432 + 3072 + 8192);
  if (i4 >= 0 && i4 < 32768) hstate[i4] = 0u;
}

// ---------------------------------------------------------------------------
// GEMM: C[M,N] = A[M,K] * Bw[N,K]^T + bias, bf16 MFMA 16x16x32.
// A row = (m>>tcs)*Ttot + t0 + (m & (Tc-1))  (handles chunked [B,T,*]).
// ---------------------------------------------------------------------------
template <typename TA, typename TC>
__global__ __launch_bounds__(256, 2) void gemm_bt(
    const TA* __restrict__ A, const float* __restrict__ Bw,
    const float* __restrict__ bias, TC* __restrict__ C,
    int K, int lda, int ldc, int tcshift, int t0, int Ttot) {
  __shared__ unsigned short As[128 * 40];
  __shared__ unsigned short Bs[128 * 40];
  const int tid = threadIdx.x;
  const int bm = blockIdx.x, bn = blockIdx.y;
  const int r = tid >> 1, hf = tid & 1;

  const int m = bm * 128 + r;
  const long arow = (long)(m >> tcshift) * Ttot + t0 + (m & ((1 << tcshift) - 1));
  const TA* ap = A + arow * (long)lda + hf * 16;
  const int n = bn * 128 + r;
  const float* bp = Bw + (long)n * K + hf * 16;

  const int wid = tid >> 6, lane = tid & 63;
  const int wm = (wid >> 1) * 64, wn = (wid & 1) * 64;
  const int m16 = lane & 15, quad = lane >> 4;

  floatx4 acc[4][4];
#pragma unroll
  for (int i = 0; i < 4; ++i)
#pragma unroll
    for (int j = 0; j < 4; ++j) acc[i][j] = 0.f;

  for (int k0 = 0; k0 < K; k0 += 32) {
    unsigned short ta[16], tb[16];
    if constexpr (std::is_same<TA, float>::value) {
      const float4* p = (const float4*)(ap + k0);
#pragma unroll
      for (int q = 0; q < 4; ++q) {
        float4 v = p[q];
        ta[q * 4 + 0] = __builtin_bit_cast(unsigned short, __float2bfloat16(v.x));
        ta[q * 4 + 1] = __builtin_bit_cast(unsigned short, __float2bfloat16(v.y));
        ta[q * 4 + 2] = __builtin_bit_cast(unsigned short, __float2bfloat16(v.z));
        ta[q * 4 + 3] = __builtin_bit_cast(unsigned short, __float2bfloat16(v.w));
      }
    } else {
      const uint4* p = (const uint4*)(ap + k0);
      *(uint4*)&ta[0] = p[0];
      *(uint4*)&ta[8] = p[1];
    }
    {
      const float4* p = (const float4*)(bp + k0);
#pragma unroll
      for (int q = 0; q < 4; ++q) {
        float4 v = p[q];
        tb[q * 4 + 0] = __builtin_bit_cast(unsigned short, __float2bfloat16(v.x));
        tb[q * 4 + 1] = __builtin_bit_cast(unsigned short, __float2bfloat16(v.y));
        tb[q * 4 + 2] = __builtin_bit_cast(unsigned short, __float2bfloat16(v.z));
        tb[q * 4 + 3] = __builtin_bit_cast(unsigned short, __float2bfloat16(v.w));
      }
    }
    *(uint4*)&As[r * 40 + hf * 16] = *(uint4*)&ta[0];
    *(uint4*)&As[r * 40 + hf * 16 + 8] = *(uint4*)&ta[8];
    *(uint4*)&Bs[r * 40 + hf * 16] = *(uint4*)&tb[0];
    *(uint4*)&Bs[r * 40 + hf * 16 + 8] = *(uint4*)&tb[8];
    __syncthreads();
    short8 af[4], bfr[4];
#pragma unroll
    for (int mt = 0; mt < 4; ++mt)
      af[mt] = *(const short8*)&As[(wm + mt * 16 + m16) * 40 + quad * 8];
#pragma unroll
    for (int nt = 0; nt < 4; ++nt)
      bfr[nt] = *(const short8*)&Bs[(wn + nt * 16 + m16) * 40 + quad * 8];
#pragma unroll
    for (int mt = 0; mt < 4; ++mt)
#pragma unroll
      for (int nt = 0; nt < 4; ++nt)
        acc[mt][nt] = __builtin_amdgcn_mfma_f32_16x16x32_bf16(af[mt], bfr[nt],
                                                              acc[mt][nt], 0, 0, 0);
    __syncthreads();
  }
#pragma unroll
  for (int mt = 0; mt < 4; ++mt)
#pragma unroll
    for (int nt = 0; nt < 4; ++nt)
#pragma unroll
      for (int rr = 0; rr < 4; ++rr) {
        int grow = bm * 128 + wm + mt * 16 + quad * 4 + rr;
        int gcol = bn * 128 + wn + nt * 16 + m16;
        float v = acc[mt][nt][rr];
        if (bias) v += bias[gcol];
        if constexpr (std::is_same<TC, float>::value)
          C[(long)grow * ldc + gcol] = v;
        else
          C[(long)grow * ldc + gcol] = __float2half(v);
      }
}

// ---------------------------------------------------------------------------
// GRU recurrence, wave-specialized, 2 raw barriers per step.
// WG (c = blk>>6, b = blk&63): batch b, h-chunk c (same-XCD for a batch).
// All 8 waves: dot2 partials (thread (j=tid&127, s=tid>>7), 192 w-regs).
// wave0: gate math for 2 h/lane, hds+hbuf store, RELEASE tag, out store.
// wave1: xg prefetch one step ahead via registers -> xbuf LDS.
// waves4-7: poll peer tag (monotonic, relaxed agent) + reload chunk.
// ---------------------------------------------------------------------------
__global__ __launch_bounds__(512, 2) void gru_rec(
    const uint32_t* __restrict__ wpack, const uint32_t* __restrict__ xgd,
    const float* __restrict__ bhh, uint32_t* __restrict__ hstate,
    uint32_t* __restrict__ outw, uint32_t* __restrict__ hbuf,
    uint32_t* __restrict__ tags, float* __restrict__ hid_out,
    int t0, int Tc, int outT, int outT0, int last) {
  const int tid = threadIdx.x;
  const int wave = tid >> 6, lane = tid & 63;
  const int s = tid >> 7;
  const int b = blockIdx.x & 63;
  const int c = blockIdx.x >> 6;

  __shared__ uint32_t hds[256];     // full h as fp16x2
  __shared__ float part[3][512];
  __shared__ uint32_t xbuf[3][64];  // x-gate dwords for this chunk's 128 j

  uint32_t w[192];
  {
    const uint32_t* wp = wpack + (size_t)(c * 4 + s) * 24576 + (tid & 127);
#pragma unroll
    for (int i = 0; i < 192; ++i) w[i] = wp[(size_t)i * 128];
  }

  if (tid < 256) hds[tid] = hstate[b * 256 + tid];

  uint32_t xp0 = 0, xp1 = 0, xp2 = 0;
  if (wave == 1) {
    size_t base = ((size_t)b * Tc) * 768 + c * 64 + lane;
    xp0 = xgd[base];
    xp1 = xgd[base + 256];
    xp2 = xgd[base + 512];
  }
  float hold0 = 0.f, hold1 = 0.f, bn0 = 0.f, bn1 = 0.f;
  if (wave == 0) {
    uint32_t hv = hstate[b * 256 + c * 64 + lane];
    __half2 hh = __builtin_bit_cast(__half2, hv);
    hold0 = __half2float(hh.x);
    hold1 = __half2float(hh.y);
    bn0 = bhh[1024 + c * 128 + 2 * lane];
    bn1 = bhh[1024 + c * 128 + 2 * lane + 1];
  }
  BARX();

  for (int tt = 0; tt < Tc; ++tt) {
    const int t = t0 + tt;
    const uint32_t tagv = (uint32_t)(t + 1);
    const int slot = t & 1;

    if (wave == 1) {
      xbuf[0][lane] = xp0;
      xbuf[1][lane] = xp1;
      xbuf[2][lane] = xp2;
      if (tt + 1 < Tc) {
        size_t base = ((size_t)b * Tc + tt + 1) * 768 + c * 64 + lane;
        xp0 = xgd[base];
        xp1 = xgd[base + 256];
        xp2 = xgd[base + 512];
      }
    }
    // dots over own k-slice (chunk s of h)
    float ar = 0.f, az = 0.f, an = 0.f;
    const int hb = s * 64;
#pragma unroll
    for (int k4 = 0; k4 < 16; ++k4) {
      uint4 u4 = *((const uint4*)&hds[hb] + k4);
      ar = fdot2f(w[(k4 * 4 + 0) * 3 + 0], u4.x, ar);
      az = fdot2f(w[(k4 * 4 + 0) * 3 + 1], u4.x, az);
      an = fdot2f(w[(k4 * 4 + 0) * 3 + 2], u4.x, an);
      ar = fdot2f(w[(k4 * 4 + 1) * 3 + 0], u4.y, ar);
      az = fdot2f(w[(k4 * 4 + 1) * 3 + 1], u4.y, az);
      an = fdot2f(w[(k4 * 4 + 1) * 3 + 2], u4.y, an);
      ar = fdot2f(w[(k4 * 4 + 2) * 3 + 0], u4.z, ar);
      az = fdot2f(w[(k4 * 4 + 2) * 3 + 1], u4.z, az);
      an = fdot2f(w[(k4 * 4 + 2) * 3 + 2], u4.z, an);
      ar = fdot2f(w[(k4 * 4 + 3) * 3 + 0], u4.w, ar);
      az = fdot2f(w[(k4 * 4 + 3) * 3 + 1], u4.w, az);
      an = fdot2f(w[(k4 * 4 + 3) * 3 + 2], u4.w, an);
    }
    part[0][tid] = ar;
    part[1][tid] = az;
    part[2][tid] = an;
    BARX();  // B1: all partials + xbuf visible

    if (wave == 0) {
      float hr0 = 0.f, hz0 = 0.f, hn0 = 0.f, hr1 = 0.f, hz1 = 0.f, hn1 = 0.f;
#pragma unroll
      for (int ss = 0; ss < 4; ++ss) {
        float2 vr = *(const float2*)&part[0][ss * 128 + 2 * lane];
        float2 vz = *(const float2*)&part[1][ss * 128 + 2 * lane];
        float2 vn = *(const float2*)&part[2][ss * 128 + 2 * lane];
        hr0 += vr.x; hr1 += vr.y;
        hz0 += vz.x; hz1 += vz.y;
        hn0 += vn.x; hn1 += vn.y;
      }
      __half2 xr = __builtin_bit_cast(__half2, xbuf[0][lane]);
      __half2 xz = __builtin_bit_cast(__half2, xbuf[1][lane]);
      __half2 xn = __builtin_bit_cast(__half2, xbuf[2][lane]);
      float r0 = sigmoid_f(__half2float(xr.x) + hr0);
      float r1 = sigmoid_f(__half2float(xr.y) + hr1);
      float z0 = sigmoid_f(__half2float(xz.x) + hz0);
      float z1 = sigmoid_f(__half2float(xz.y) + hz1);
      float n0 = tanh_f(__half2float(xn.x) + r0 * (hn0 + bn0));
      float n1 = tanh_f(__half2float(xn.y) + r1 * (hn1 + bn1));
      float h0 = (1.f - z0) * n0 + z0 * hold0;
      float h1 = (1.f - z1) * n1 + z1 * hold1;
      hold0 = h0;
      hold1 = h1;
      uint32_t hd = pack_h2(h0, h1);
      hds[c * 64 + lane] = hd;
      __hip_atomic_store(&hbuf[slot * 16384 + b * 256 + c * 64 + lane], hd,
                         __ATOMIC_RELAXED, __HIP_MEMORY_SCOPE_AGENT);
      if (lane == 0)
        __hip_atomic_store(&tags[(b * 4 + c) * 16], tagv, __ATOMIC_RELEASE,
                           __HIP_MEMORY_SCOPE_AGENT);
      // out store after the tag: never drained on the critical path
      outw[((size_t)b * outT + outT0 + tt) * 256 + c * 64 + lane] = pack_bf2(h0, h1);
    }
    if (wave >= 4) {
      int cc = wave - 4;
      if (cc != c) {
        uint32_t* tp = &tags[(b * 4 + cc) * 16];
        while (__hip_atomic_load(tp, __ATOMIC_RELAXED, __HIP_MEMORY_SCOPE_AGENT) < tagv) {
        }
        __builtin_amdgcn_fence(__ATOMIC_ACQUIRE, "agent");
        uint32_t v = __hip_atomic_load(&hbuf[slot * 16384 + b * 256 + cc * 64 + lane],
                                       __ATOMIC_RELAXED, __HIP_MEMORY_SCOPE_AGENT);
        hds[cc * 64 + lane] = v;
      }
    }
    BARX();  // B2: hds fully updated to h(t+1)
  }

  if (tid < 256) hstate[b * 256 + tid] = hds[tid];
  if (last && tid < 128) {
    int jp = c * 128 + tid;
    hid_out[b * 512 + jp] = __half2float(((const __half*)hds)[jp]);
  }
}

// ---------------------------------------------------------------------------
extern "C" void kernel_launch(void* const* d_in, const int* in_sizes, int n_in,
                              void* d_out, int out_size, void* d_ws, size_t ws_size,
                              hipStream_t stream) {
  const float* x = (const float*)d_in[0];
  const float* W_ih0 = (const float*)d_in[1];
  const float* W_hh0 = (const float*)d_in[2];
  const float* b_ih0 = (const float*)d_in[3];
  const float* b_hh0 = (const float*)d_in[4];
  const float* W_ih1 = (const float*)d_in[5];
  const float* W_hh1 = (const float*)d_in[6];
  const float* b_ih1 = (const float*)d_in[7];
  const float* b_hh1 = (const float*)d_in[8];
  const float* fc_w = (const float*)d_in[9];
  const float* fc_b = (const float*)d_in[10];
  float* out = (float*)d_out;

  char* p = (char*)d_ws;
  size_t off = 0;
  auto alloc = [&](size_t bytes) -> void* {
    void* r = p + off;
    off = (off + bytes + 255) & ~(size_t)255;
    return r;
  };
  uint32_t* wpack = (uint32_t*)alloc((size_t)786432 * 4);
  float* biasv = (float*)alloc((size_t)3072 * 4);
  uint32_t* tags = (uint32_t*)alloc((size_t)8192 * 4);   // 2 layers x 64b x 4c x16 pad
  uint32_t* hstate = (uint32_t*)alloc((size_t)32768 * 4);
  uint32_t* hbuf = (uint32_t*)alloc((size_t)2 * 2 * 64 * 256 * 4);  // per layer
  __hip_bfloat16* out1 = (__hip_bfloat16*)alloc((size_t)B_ * T_ * H_ * 2);

  int Tc = 1024;
  while (Tc > 64) {
    size_t need = (size_t)B_ * Tc * H_ * 2 + (size_t)B_ * Tc * G3_ * 2 + 1024;
    if (off + need <= ws_size) break;
    Tc >>= 1;
  }
  __hip_bfloat16* out0c = (__hip_bfloat16*)alloc((size_t)B_ * Tc * H_ * 2);
  __half* xg = (__half*)alloc((size_t)B_ * Tc * G3_ * 2);
  int tcs = __builtin_ctz(Tc);

  init_kernel<<<3244, 256, 0, stream>>>(W_hh0, W_hh1, b_ih0, b_hh0, b_ih1, b_hh1,
                                        wpack, biasv, tags, hstate);

  for (int t0 = 0; t0 < 1024; t0 += Tc) {
    const int M = B_ * Tc;
    const int last = (t0 + Tc) == 1024;
    // ---- layer 0 ----
    {
      dim3 gg(M / 128, G3_ / 128);
      gemm_bt<float, __half><<<gg, 256, 0, stream>>>(x, W_ih0, biasv, xg, I_, I_,
                                                     G3_, tcs, t0, 1024);
      gru_rec<<<256, 512, 0, stream>>>(wpack, (const uint32_t*)xg, b_hh0, hstate,
                                       (uint32_t*)out0c, hbuf, tags,
                                       out + 16777216, t0, Tc, Tc, 0, last);
    }
    // ---- layer 1 ----
    {
      dim3 gg(M / 128, G3_ / 128);
      gemm_bt<__hip_bfloat16, __half><<<gg, 256, 0, stream>>>(
          out0c, W_ih1, biasv + 1536, xg, H_, H_, G3_, tcs, 0, Tc);
      gru_rec<<<256, 512, 0, stream>>>(wpack + 393216, (const uint32_t*)xg, b_hh1,
                                       hstate + 16384, (uint32_t*)out1,
                                       hbuf + 32768, tags + 4096,
                                       out + 16777216 + 32768, t0, Tc, 1024, t0, last);
    }
  }
  // FC: [65536,512] x fc_w[256,512]^T + fc_b -> d_out fp32
  dim3 gf(65536 / 128, O_ / 128);
  gemm_bt<__hip_bfloat16, float><<<gf, 256, 0, stream>>>(out1, fc_w, fc_b, out,
                                                         H_, H_, O_, 10, 0, 1024);
}

// Round 4
// 4416.459 us; speedup vs baseline: 4.0604x; 4.0604x over previous
//
#include <hip/hip_runtime.h>
#include <hip/hip_bf16.h>
#include <hip/hip_fp16.h>
#include <stdint.h>
#include <type_traits>

// Problem constants
#define B_ 64
#define T_ 1024
#define I_ 256
#define H_ 512
#define G3_ 1536
#define O_ 256

typedef __attribute__((ext_vector_type(4))) float floatx4;
typedef __attribute__((ext_vector_type(8))) short short8;
typedef __attribute__((ext_vector_type(2))) _Float16 half2v;

// Raw workgroup barrier: drains LDS only, NOT vmcnt. Keeps HBM/LLC ops
// (out stores, xg prefetch, packet stores) off the per-step critical path.
#define BARX() __asm__ volatile("s_waitcnt lgkmcnt(0)\n\ts_barrier" ::: "memory")

static __device__ __forceinline__ float fdot2f(uint32_t a, uint32_t b, float c) {
#if __has_builtin(__builtin_amdgcn_fdot2)
  return __builtin_amdgcn_fdot2(__builtin_bit_cast(half2v, a),
                                __builtin_bit_cast(half2v, b), c, false);
#else
  __half2 ha = __builtin_bit_cast(__half2, a);
  __half2 hb = __builtin_bit_cast(__half2, b);
  float2 fa = __half22float2(ha), fb = __half22float2(hb);
  return c + fa.x * fb.x + fa.y * fb.y;
#endif
}

static __device__ __forceinline__ float sigmoid_f(float x) {
  float e = __expf(-fabsf(x));
  float a = 1.f / (1.f + e);
  return x >= 0.f ? a : 1.f - a;
}
static __device__ __forceinline__ float tanh_f(float x) {
  float e = __expf(-2.f * fabsf(x));
  float a = (1.f - e) / (1.f + e);
  return x >= 0.f ? a : -a;
}
static __device__ __forceinline__ uint32_t pack_h2(float a, float b) {
  return (uint32_t)__half_as_ushort(__float2half(a)) |
         ((uint32_t)__half_as_ushort(__float2half(b)) << 16);
}
static __device__ __forceinline__ uint32_t pack_bf2(float a, float b) {
  return (uint32_t)__builtin_bit_cast(unsigned short, __float2bfloat16(a)) |
         ((uint32_t)__builtin_bit_cast(unsigned short, __float2bfloat16(b)) << 16);
}

// ---------------------------------------------------------------------------
// init: pack W_hh -> fp16 register layout, combined biases, zero hstate.
// wpack dword index: j + 128*g + 384*kk + 24576*s + 98304*c + 393216*l
// Packets need NO init: 0xAAAAAAAA poison never equals a tag (tags are 1..1024).
// ---------------------------------------------------------------------------
__global__ void init_kernel(const float* __restrict__ Whh0, const float* __restrict__ Whh1,
                            const float* __restrict__ bih0, const float* __restrict__ bhh0,
                            const float* __restrict__ bih1, const float* __restrict__ bhh1,
                            uint32_t* __restrict__ wpack, float* __restrict__ biasv,
                            uint32_t* __restrict__ hstate) {
  int idx = blockIdx.x * 256 + threadIdx.x;
  if (idx < 786432) {
    int l = idx / 393216, rem = idx % 393216;
    int j = rem & 127;
    int g = (rem >> 7) % 3;
    int kk = (rem / 384) & 63;
    int s = (rem / 24576) & 3;
    int c = rem / 98304;
    const float* W = l ? Whh1 : Whh0;
    int row = g * 512 + c * 128 + j;
    int k = s * 128 + kk * 2;
    uint32_t lo = __half_as_ushort(__float2half(W[(size_t)row * 512 + k]));
    uint32_t hi = __half_as_ushort(__float2half(W[(size_t)row * 512 + k + 1]));
    wpack[idx] = lo | (hi << 16);
  }
  int i2 = idx - 786432;
  if (i2 >= 0 && i2 < 3072) {
    int l = i2 / 1536, n = i2 % 1536;
    const float* bi = l ? bih1 : bih0;
    const float* bh = l ? bhh1 : bhh0;
    biasv[i2] = bi[n] + (n < 1024 ? bh[n] : 0.f);
  }
  int i3 = idx - (786432 + 3072);
  if (i3 >= 0 && i3 < 32768) hstate[i3] = 0u;
}

// ---------------------------------------------------------------------------
// GEMM: C[M,N] = A[M,K] * Bw[N,K]^T + bias, bf16 MFMA 16x16x32.
// A row = (m>>tcs)*Ttot + t0 + (m & (Tc-1))  (handles chunked [B,T,*]).
// ---------------------------------------------------------------------------
template <typename TA, typename TC>
__global__ __launch_bounds__(256, 2) void gemm_bt(
    const TA* __restrict__ A, const float* __restrict__ Bw,
    const float* __restrict__ bias, TC* __restrict__ C,
    int K, int lda, int ldc, int tcshift, int t0, int Ttot) {
  __shared__ unsigned short As[128 * 40];
  __shared__ unsigned short Bs[128 * 40];
  const int tid = threadIdx.x;
  const int bm = blockIdx.x, bn = blockIdx.y;
  const int r = tid >> 1, hf = tid & 1;

  const int m = bm * 128 + r;
  const long arow = (long)(m >> tcshift) * Ttot + t0 + (m & ((1 << tcshift) - 1));
  const TA* ap = A + arow * (long)lda + hf * 16;
  const int n = bn * 128 + r;
  const float* bp = Bw + (long)n * K + hf * 16;

  const int wid = tid >> 6, lane = tid & 63;
  const int wm = (wid >> 1) * 64, wn = (wid & 1) * 64;
  const int m16 = lane & 15, quad = lane >> 4;

  floatx4 acc[4][4];
#pragma unroll
  for (int i = 0; i < 4; ++i)
#pragma unroll
    for (int j = 0; j < 4; ++j) acc[i][j] = 0.f;

  for (int k0 = 0; k0 < K; k0 += 32) {
    unsigned short ta[16], tb[16];
    if constexpr (std::is_same<TA, float>::value) {
      const float4* p = (const float4*)(ap + k0);
#pragma unroll
      for (int q = 0; q < 4; ++q) {
        float4 v = p[q];
        ta[q * 4 + 0] = __builtin_bit_cast(unsigned short, __float2bfloat16(v.x));
        ta[q * 4 + 1] = __builtin_bit_cast(unsigned short, __float2bfloat16(v.y));
        ta[q * 4 + 2] = __builtin_bit_cast(unsigned short, __float2bfloat16(v.z));
        ta[q * 4 + 3] = __builtin_bit_cast(unsigned short, __float2bfloat16(v.w));
      }
    } else {
      const uint4* p = (const uint4*)(ap + k0);
      *(uint4*)&ta[0] = p[0];
      *(uint4*)&ta[8] = p[1];
    }
    {
      const float4* p = (const float4*)(bp + k0);
#pragma unroll
      for (int q = 0; q < 4; ++q) {
        float4 v = p[q];
        tb[q * 4 + 0] = __builtin_bit_cast(unsigned short, __float2bfloat16(v.x));
        tb[q * 4 + 1] = __builtin_bit_cast(unsigned short, __float2bfloat16(v.y));
        tb[q * 4 + 2] = __builtin_bit_cast(unsigned short, __float2bfloat16(v.z));
        tb[q * 4 + 3] = __builtin_bit_cast(unsigned short, __float2bfloat16(v.w));
      }
    }
    *(uint4*)&As[r * 40 + hf * 16] = *(uint4*)&ta[0];
    *(uint4*)&As[r * 40 + hf * 16 + 8] = *(uint4*)&ta[8];
    *(uint4*)&Bs[r * 40 + hf * 16] = *(uint4*)&tb[0];
    *(uint4*)&Bs[r * 40 + hf * 16 + 8] = *(uint4*)&tb[8];
    __syncthreads();
    short8 af[4], bfr[4];
#pragma unroll
    for (int mt = 0; mt < 4; ++mt)
      af[mt] = *(const short8*)&As[(wm + mt * 16 + m16) * 40 + quad * 8];
#pragma unroll
    for (int nt = 0; nt < 4; ++nt)
      bfr[nt] = *(const short8*)&Bs[(wn + nt * 16 + m16) * 40 + quad * 8];
#pragma unroll
    for (int mt = 0; mt < 4; ++mt)
#pragma unroll
      for (int nt = 0; nt < 4; ++nt)
        acc[mt][nt] = __builtin_amdgcn_mfma_f32_16x16x32_bf16(af[mt], bfr[nt],
                                                              acc[mt][nt], 0, 0, 0);
    __syncthreads();
  }
#pragma unroll
  for (int mt = 0; mt < 4; ++mt)
#pragma unroll
    for (int nt = 0; nt < 4; ++nt)
#pragma unroll
      for (int rr = 0; rr < 4; ++rr) {
        int grow = bm * 128 + wm + mt * 16 + quad * 4 + rr;
        int gcol = bn * 128 + wn + nt * 16 + m16;
        float v = acc[mt][nt][rr];
        if (bias) v += bias[gcol];
        if constexpr (std::is_same<TC, float>::value)
          C[(long)grow * ldc + gcol] = v;
        else
          C[(long)grow * ldc + gcol] = __float2half(v);
      }
}

// ---------------------------------------------------------------------------
// GRU recurrence, packet-fused exchange, 2 raw barriers per step.
// WG (c = blk>>6, b = blk&63): batch b, h-chunk c.
// All 8 waves: dot2 partials (thread (j=tid&127, s=tid>>7), 192 w-regs).
// wave0: gate math for 2 h/lane; publishes ONE u64 packet {h2, tag} per lane
//        (single relaxed agent atomic store -- no release drain needed).
// wave1: xg prefetch one step ahead via registers -> xbuf LDS.
// waves4-7: poll peer packet word until tag matches; data rides in the same
//           8B read (same-address dependency -> no acquire fence, no 2nd load).
// ---------------------------------------------------------------------------
__global__ __launch_bounds__(512, 2) void gru_rec(
    const uint32_t* __restrict__ wpack, const uint32_t* __restrict__ xgd,
    const float* __restrict__ bhh, uint32_t* __restrict__ hstate,
    uint32_t* __restrict__ outw, uint64_t* __restrict__ pkts,
    float* __restrict__ hid_out,
    int t0, int Tc, int outT, int outT0, int last) {
  const int tid = threadIdx.x;
  const int wave = tid >> 6, lane = tid & 63;
  const int s = tid >> 7;
  const int b = blockIdx.x & 63;
  const int c = blockIdx.x >> 6;

  __shared__ uint32_t hds[256];     // full h as fp16x2
  __shared__ float part[3][512];
  __shared__ uint32_t xbuf[3][64];  // x-gate dwords for this chunk's 128 j

  uint32_t w[192];
  {
    const uint32_t* wp = wpack + (size_t)(c * 4 + s) * 24576 + (tid & 127);
#pragma unroll
    for (int i = 0; i < 192; ++i) w[i] = wp[(size_t)i * 128];
  }

  if (tid < 256) hds[tid] = hstate[b * 256 + tid];

  uint32_t xp0 = 0, xp1 = 0, xp2 = 0;
  if (wave == 1) {
    size_t base = ((size_t)b * Tc) * 768 + c * 64 + lane;
    xp0 = xgd[base];
    xp1 = xgd[base + 256];
    xp2 = xgd[base + 512];
  }
  float hold0 = 0.f, hold1 = 0.f, bn0 = 0.f, bn1 = 0.f;
  if (wave == 0) {
    uint32_t hv = hstate[b * 256 + c * 64 + lane];
    __half2 hh = __builtin_bit_cast(__half2, hv);
    hold0 = __half2float(hh.x);
    hold1 = __half2float(hh.y);
    bn0 = bhh[1024 + c * 128 + 2 * lane];
    bn1 = bhh[1024 + c * 128 + 2 * lane + 1];
  }
  BARX();

  for (int tt = 0; tt < Tc; ++tt) {
    const int t = t0 + tt;
    const uint32_t tagv = (uint32_t)(t + 1);
    const int slot = t & 1;

    if (wave == 1) {
      xbuf[0][lane] = xp0;
      xbuf[1][lane] = xp1;
      xbuf[2][lane] = xp2;
      if (tt + 1 < Tc) {
        size_t base = ((size_t)b * Tc + tt + 1) * 768 + c * 64 + lane;
        xp0 = xgd[base];
        xp1 = xgd[base + 256];
        xp2 = xgd[base + 512];
      }
    }
    // dots over own k-slice (chunk s of h)
    float ar = 0.f, az = 0.f, an = 0.f;
    const int hb = s * 64;
#pragma unroll
    for (int k4 = 0; k4 < 16; ++k4) {
      uint4 u4 = *((const uint4*)&hds[hb] + k4);
      ar = fdot2f(w[(k4 * 4 + 0) * 3 + 0], u4.x, ar);
      az = fdot2f(w[(k4 * 4 + 0) * 3 + 1], u4.x, az);
      an = fdot2f(w[(k4 * 4 + 0) * 3 + 2], u4.x, an);
      ar = fdot2f(w[(k4 * 4 + 1) * 3 + 0], u4.y, ar);
      az = fdot2f(w[(k4 * 4 + 1) * 3 + 1], u4.y, az);
      an = fdot2f(w[(k4 * 4 + 1) * 3 + 2], u4.y, an);
      ar = fdot2f(w[(k4 * 4 + 2) * 3 + 0], u4.z, ar);
      az = fdot2f(w[(k4 * 4 + 2) * 3 + 1], u4.z, az);
      an = fdot2f(w[(k4 * 4 + 2) * 3 + 2], u4.z, an);
      ar = fdot2f(w[(k4 * 4 + 3) * 3 + 0], u4.w, ar);
      az = fdot2f(w[(k4 * 4 + 3) * 3 + 1], u4.w, az);
      an = fdot2f(w[(k4 * 4 + 3) * 3 + 2], u4.w, an);
    }
    part[0][tid] = ar;
    part[1][tid] = az;
    part[2][tid] = an;
    BARX();  // B1: all partials + xbuf visible

    if (wave == 0) {
      float hr0 = 0.f, hz0 = 0.f, hn0 = 0.f, hr1 = 0.f, hz1 = 0.f, hn1 = 0.f;
#pragma unroll
      for (int ss = 0; ss < 4; ++ss) {
        float2 vr = *(const float2*)&part[0][ss * 128 + 2 * lane];
        float2 vz = *(const float2*)&part[1][ss * 128 + 2 * lane];
        float2 vn = *(const float2*)&part[2][ss * 128 + 2 * lane];
        hr0 += vr.x; hr1 += vr.y;
        hz0 += vz.x; hz1 += vz.y;
        hn0 += vn.x; hn1 += vn.y;
      }
      __half2 xr = __builtin_bit_cast(__half2, xbuf[0][lane]);
      __half2 xz = __builtin_bit_cast(__half2, xbuf[1][lane]);
      __half2 xn = __builtin_bit_cast(__half2, xbuf[2][lane]);
      float r0 = sigmoid_f(__half2float(xr.x) + hr0);
      float r1 = sigmoid_f(__half2float(xr.y) + hr1);
      float z0 = sigmoid_f(__half2float(xz.x) + hz0);
      float z1 = sigmoid_f(__half2float(xz.y) + hz1);
      float n0 = tanh_f(__half2float(xn.x) + r0 * (hn0 + bn0));
      float n1 = tanh_f(__half2float(xn.y) + r1 * (hn1 + bn1));
      float h0 = (1.f - z0) * n0 + z0 * hold0;
      float h1 = (1.f - z1) * n1 + z1 * hold1;
      hold0 = h0;
      hold1 = h1;
      uint32_t hd = pack_h2(h0, h1);
      hds[c * 64 + lane] = hd;
      // ONE 8B packet: data + tag together. No drain, no fence, no 2nd load.
      uint64_t pk = (uint64_t)hd | ((uint64_t)tagv << 32);
      __hip_atomic_store(&pkts[(((size_t)slot * 64 + b) * 4 + c) * 64 + lane], pk,
                         __ATOMIC_RELAXED, __HIP_MEMORY_SCOPE_AGENT);
      // out store after the packet: never drained on the critical path
      outw[((size_t)b * outT + outT0 + tt) * 256 + c * 64 + lane] = pack_bf2(h0, h1);
    }
    if (wave >= 4) {
      int cc = wave - 4;
      if (cc != c) {
        const uint64_t* pp = &pkts[(((size_t)slot * 64 + b) * 4 + cc) * 64 + lane];
        uint64_t v;
        do {
          v = __hip_atomic_load(pp, __ATOMIC_RELAXED, __HIP_MEMORY_SCOPE_AGENT);
        } while ((uint32_t)(v >> 32) != tagv);
        hds[cc * 64 + lane] = (uint32_t)v;
      }
    }
    BARX();  // B2: hds fully updated to h(t+1)
  }

  if (tid < 256) hstate[b * 256 + tid] = hds[tid];
  if (last && tid < 128) {
    int jp = c * 128 + tid;
    hid_out[b * 512 + jp] = __half2float(((const __half*)hds)[jp]);
  }
}

// ---------------------------------------------------------------------------
extern "C" void kernel_launch(void* const* d_in, const int* in_sizes, int n_in,
                              void* d_out, int out_size, void* d_ws, size_t ws_size,
                              hipStream_t stream) {
  const float* x = (const float*)d_in[0];
  const float* W_ih0 = (const float*)d_in[1];
  const float* W_hh0 = (const float*)d_in[2];
  const float* b_ih0 = (const float*)d_in[3];
  const float* b_hh0 = (const float*)d_in[4];
  const float* W_ih1 = (const float*)d_in[5];
  const float* W_hh1 = (const float*)d_in[6];
  const float* b_ih1 = (const float*)d_in[7];
  const float* b_hh1 = (const float*)d_in[8];
  const float* fc_w = (const float*)d_in[9];
  const float* fc_b = (const float*)d_in[10];
  float* out = (float*)d_out;

  char* p = (char*)d_ws;
  size_t off = 0;
  auto alloc = [&](size_t bytes) -> void* {
    void* r = p + off;
    off = (off + bytes + 255) & ~(size_t)255;
    return r;
  };
  uint32_t* wpack = (uint32_t*)alloc((size_t)786432 * 4);
  float* biasv = (float*)alloc((size_t)3072 * 4);
  uint32_t* hstate = (uint32_t*)alloc((size_t)32768 * 4);
  // packets: 2 layers x 2 slots x 64 batch x 4 chunk x 64 lane x u64
  uint64_t* pkts = (uint64_t*)alloc((size_t)2 * 2 * 64 * 4 * 64 * 8);
  __hip_bfloat16* out1 = (__hip_bfloat16*)alloc((size_t)B_ * T_ * H_ * 2);

  int Tc = 1024;
  while (Tc > 64) {
    size_t need = (size_t)B_ * Tc * H_ * 2 + (size_t)B_ * Tc * G3_ * 2 + 1024;
    if (off + need <= ws_size) break;
    Tc >>= 1;
  }
  __hip_bfloat16* out0c = (__hip_bfloat16*)alloc((size_t)B_ * Tc * H_ * 2);
  __half* xg = (__half*)alloc((size_t)B_ * Tc * G3_ * 2);
  int tcs = __builtin_ctz(Tc);

  init_kernel<<<3212, 256, 0, stream>>>(W_hh0, W_hh1, b_ih0, b_hh0, b_ih1, b_hh1,
                                        wpack, biasv, hstate);

  for (int t0 = 0; t0 < 1024; t0 += Tc) {
    const int M = B_ * Tc;
    const int last = (t0 + Tc) == 1024;
    // ---- layer 0 ----
    {
      dim3 gg(M / 128, G3_ / 128);
      gemm_bt<float, __half><<<gg, 256, 0, stream>>>(x, W_ih0, biasv, xg, I_, I_,
                                                     G3_, tcs, t0, 1024);
      gru_rec<<<256, 512, 0, stream>>>(wpack, (const uint32_t*)xg, b_hh0, hstate,
                                       (uint32_t*)out0c, pkts,
                                       out + 16777216, t0, Tc, Tc, 0, last);
    }
    // ---- layer 1 ----
    {
      dim3 gg(M / 128, G3_ / 128);
      gemm_bt<__hip_bfloat16, __half><<<gg, 256, 0, stream>>>(
          out0c, W_ih1, biasv + 1536, xg, H_, H_, G3_, tcs, 0, Tc);
      gru_rec<<<256, 512, 0, stream>>>(wpack + 393216, (const uint32_t*)xg, b_hh1,
                                       hstate + 16384, (uint32_t*)out1,
                                       pkts + 32768,
                                       out + 16777216 + 32768, t0, Tc, 1024, t0, last);
    }
  }
  // FC: [65536,512] x fc_w[256,512]^T + fc_b -> d_out fp32
  dim3 gf(65536 / 128, O_ / 128);
  gemm_bt<__hip_bfloat16, float><<<gf, 256, 0, stream>>>(out1, fc_w, fc_b, out,
                                                         H_, H_, O_, 10, 0, 1024);
}

// Round 5
// 4398.238 us; speedup vs baseline: 4.0772x; 1.0041x over previous
//
#include <hip/hip_runtime.h>
#include <hip/hip_bf16.h>
#include <hip/hip_fp16.h>
#include <stdint.h>
#include <type_traits>

// Problem constants
#define B_ 64
#define T_ 1024
#define I_ 256
#define H_ 512
#define G3_ 1536
#define O_ 256

typedef __attribute__((ext_vector_type(4))) float floatx4;
typedef __attribute__((ext_vector_type(8))) short short8;
typedef __attribute__((ext_vector_type(2))) _Float16 half2v;

// Raw workgroup barrier: drains LDS only, NOT vmcnt. Keeps HBM/LLC ops
// (out stores, xg prefetch, packet stores) off the per-step critical path.
#define BARX() __asm__ volatile("s_waitcnt lgkmcnt(0)\n\ts_barrier" ::: "memory")

static __device__ __forceinline__ float fdot2f(uint32_t a, uint32_t b, float c) {
#if __has_builtin(__builtin_amdgcn_fdot2)
  return __builtin_amdgcn_fdot2(__builtin_bit_cast(half2v, a),
                                __builtin_bit_cast(half2v, b), c, false);
#else
  __half2 ha = __builtin_bit_cast(__half2, a);
  __half2 hb = __builtin_bit_cast(__half2, b);
  float2 fa = __half22float2(ha), fb = __half22float2(hb);
  return c + fa.x * fb.x + fa.y * fb.y;
#endif
}

static __device__ __forceinline__ float sigmoid_f(float x) {
  float e = __expf(-fabsf(x));
  float a = 1.f / (1.f + e);
  return x >= 0.f ? a : 1.f - a;
}
static __device__ __forceinline__ float tanh_f(float x) {
  float e = __expf(-2.f * fabsf(x));
  float a = (1.f - e) / (1.f + e);
  return x >= 0.f ? a : -a;
}
static __device__ __forceinline__ uint32_t pack_h2(float a, float b) {
  return (uint32_t)__half_as_ushort(__float2half(a)) |
         ((uint32_t)__half_as_ushort(__float2half(b)) << 16);
}
static __device__ __forceinline__ uint32_t pack_bf2(float a, float b) {
  return (uint32_t)__builtin_bit_cast(unsigned short, __float2bfloat16(a)) |
         ((uint32_t)__builtin_bit_cast(unsigned short, __float2bfloat16(b)) << 16);
}

// ---------------------------------------------------------------------------
// init: pack W_hh -> fp16 register layout, combined biases, zero hstate.
// wpack dword index: j + 128*g + 384*kk + 24576*s + 98304*c + 393216*l
// Packets need NO init: 0xAAAAAAAA poison never equals a tag (tags <= 1025).
// ---------------------------------------------------------------------------
__global__ void init_kernel(const float* __restrict__ Whh0, const float* __restrict__ Whh1,
                            const float* __restrict__ bih0, const float* __restrict__ bhh0,
                            const float* __restrict__ bih1, const float* __restrict__ bhh1,
                            uint32_t* __restrict__ wpack, float* __restrict__ biasv,
                            uint32_t* __restrict__ hstate) {
  int idx = blockIdx.x * 256 + threadIdx.x;
  if (idx < 786432) {
    int l = idx / 393216, rem = idx % 393216;
    int j = rem & 127;
    int g = (rem >> 7) % 3;
    int kk = (rem / 384) & 63;
    int s = (rem / 24576) & 3;
    int c = rem / 98304;
    const float* W = l ? Whh1 : Whh0;
    int row = g * 512 + c * 128 + j;
    int k = s * 128 + kk * 2;
    uint32_t lo = __half_as_ushort(__float2half(W[(size_t)row * 512 + k]));
    uint32_t hi = __half_as_ushort(__float2half(W[(size_t)row * 512 + k + 1]));
    wpack[idx] = lo | (hi << 16);
  }
  int i2 = idx - 786432;
  if (i2 >= 0 && i2 < 3072) {
    int l = i2 / 1536, n = i2 % 1536;
    const float* bi = l ? bih1 : bih0;
    const float* bh = l ? bhh1 : bhh0;
    biasv[i2] = bi[n] + (n < 1024 ? bh[n] : 0.f);
  }
  int i3 = idx - (786432 + 3072);
  if (i3 >= 0 && i3 < 32768) hstate[i3] = 0u;
}

// ---------------------------------------------------------------------------
// GEMM: C[M,N] = A[M,K] * Bw[N,K]^T + bias, bf16 MFMA 16x16x32.
// A row = (m>>tcs)*Ttot + t0 + (m & (Tc-1))  (handles chunked [B,T,*]).
// ---------------------------------------------------------------------------
template <typename TA, typename TC>
__global__ __launch_bounds__(256, 2) void gemm_bt(
    const TA* __restrict__ A, const float* __restrict__ Bw,
    const float* __restrict__ bias, TC* __restrict__ C,
    int K, int lda, int ldc, int tcshift, int t0, int Ttot) {
  __shared__ unsigned short As[128 * 40];
  __shared__ unsigned short Bs[128 * 40];
  const int tid = threadIdx.x;
  const int bm = blockIdx.x, bn = blockIdx.y;
  const int r = tid >> 1, hf = tid & 1;

  const int m = bm * 128 + r;
  const long arow = (long)(m >> tcshift) * Ttot + t0 + (m & ((1 << tcshift) - 1));
  const TA* ap = A + arow * (long)lda + hf * 16;
  const int n = bn * 128 + r;
  const float* bp = Bw + (long)n * K + hf * 16;

  const int wid = tid >> 6, lane = tid & 63;
  const int wm = (wid >> 1) * 64, wn = (wid & 1) * 64;
  const int m16 = lane & 15, quad = lane >> 4;

  floatx4 acc[4][4];
#pragma unroll
  for (int i = 0; i < 4; ++i)
#pragma unroll
    for (int j = 0; j < 4; ++j) acc[i][j] = 0.f;

  for (int k0 = 0; k0 < K; k0 += 32) {
    unsigned short ta[16], tb[16];
    if constexpr (std::is_same<TA, float>::value) {
      const float4* p = (const float4*)(ap + k0);
#pragma unroll
      for (int q = 0; q < 4; ++q) {
        float4 v = p[q];
        ta[q * 4 + 0] = __builtin_bit_cast(unsigned short, __float2bfloat16(v.x));
        ta[q * 4 + 1] = __builtin_bit_cast(unsigned short, __float2bfloat16(v.y));
        ta[q * 4 + 2] = __builtin_bit_cast(unsigned short, __float2bfloat16(v.z));
        ta[q * 4 + 3] = __builtin_bit_cast(unsigned short, __float2bfloat16(v.w));
      }
    } else {
      const uint4* p = (const uint4*)(ap + k0);
      *(uint4*)&ta[0] = p[0];
      *(uint4*)&ta[8] = p[1];
    }
    {
      const float4* p = (const float4*)(bp + k0);
#pragma unroll
      for (int q = 0; q < 4; ++q) {
        float4 v = p[q];
        tb[q * 4 + 0] = __builtin_bit_cast(unsigned short, __float2bfloat16(v.x));
        tb[q * 4 + 1] = __builtin_bit_cast(unsigned short, __float2bfloat16(v.y));
        tb[q * 4 + 2] = __builtin_bit_cast(unsigned short, __float2bfloat16(v.z));
        tb[q * 4 + 3] = __builtin_bit_cast(unsigned short, __float2bfloat16(v.w));
      }
    }
    *(uint4*)&As[r * 40 + hf * 16] = *(uint4*)&ta[0];
    *(uint4*)&As[r * 40 + hf * 16 + 8] = *(uint4*)&ta[8];
    *(uint4*)&Bs[r * 40 + hf * 16] = *(uint4*)&tb[0];
    *(uint4*)&Bs[r * 40 + hf * 16 + 8] = *(uint4*)&tb[8];
    __syncthreads();
    short8 af[4], bfr[4];
#pragma unroll
    for (int mt = 0; mt < 4; ++mt)
      af[mt] = *(const short8*)&As[(wm + mt * 16 + m16) * 40 + quad * 8];
#pragma unroll
    for (int nt = 0; nt < 4; ++nt)
      bfr[nt] = *(const short8*)&Bs[(wn + nt * 16 + m16) * 40 + quad * 8];
#pragma unroll
    for (int mt = 0; mt < 4; ++mt)
#pragma unroll
      for (int nt = 0; nt < 4; ++nt)
        acc[mt][nt] = __builtin_amdgcn_mfma_f32_16x16x32_bf16(af[mt], bfr[nt],
                                                              acc[mt][nt], 0, 0, 0);
    __syncthreads();
  }
#pragma unroll
  for (int mt = 0; mt < 4; ++mt)
#pragma unroll
    for (int nt = 0; nt < 4; ++nt)
#pragma unroll
      for (int rr = 0; rr < 4; ++rr) {
        int grow = bm * 128 + wm + mt * 16 + quad * 4 + rr;
        int gcol = bn * 128 + wn + nt * 16 + m16;
        float v = acc[mt][nt][rr];
        if (bias) v += bias[gcol];
        if constexpr (std::is_same<TC, float>::value)
          C[(long)grow * ldc + gcol] = v;
        else
          C[(long)grow * ldc + gcol] = __float2half(v);
      }
}

// ---------------------------------------------------------------------------
// GRU recurrence, register-routed exchange, ONE barrier per step.
// WG (c = blk>>6, b = blk&63): batch b, h-chunk c.
// Wave w consumes only h-chunk s = w>>1 for its dot slice, so each wave polls
// its own chunk's packets directly (lane <-> h-pair 1:1), drops them in a
// per-chunk LDS strip (same-wave lgkm ordering; paired wave writes identical
// values -> benign), and dots immediately. No B2. part[] is parity
// double-buffered; the publish-implies-consumed induction across WGs makes
// two-step reuse safe with the single barrier.
// wave0: reduce + gates + publish packets {h2,tag} + out store + xg prefetch.
// ---------------------------------------------------------------------------
__global__ __launch_bounds__(512, 2) void gru_rec(
    const uint32_t* __restrict__ wpack, const uint32_t* __restrict__ xgd,
    const float* __restrict__ bhh, uint32_t* __restrict__ hstate,
    uint32_t* __restrict__ outw, uint64_t* __restrict__ pkts,
    float* __restrict__ hid_out,
    int t0, int Tc, int outT, int outT0, int last) {
  const int tid = threadIdx.x;
  const int wave = tid >> 6, lane = tid & 63;
  const int s = tid >> 7;  // k-slice / consumed h-chunk (= wave>>1)
  const int b = blockIdx.x & 63;
  const int c = blockIdx.x >> 6;

  __shared__ uint32_t hbw[4][64];     // per-chunk h strips (fp16x2)
  __shared__ float part[2][3][512];   // parity-double-buffered partials

  uint32_t w[192];
  {
    const uint32_t* wp = wpack + (size_t)(c * 4 + s) * 24576 + (tid & 127);
#pragma unroll
    for (int i = 0; i < 192; ++i) w[i] = wp[(size_t)i * 128];
  }

  // wave0 persistent state: running h (2 per lane), n-bias, prefetched xg
  float hold0 = 0.f, hold1 = 0.f, bn0 = 0.f, bn1 = 0.f;
  uint32_t xrw = 0, xzw = 0, xnw = 0;
  if (wave == 0) {
    uint32_t hv = hstate[b * 256 + c * 64 + lane];
    __half2 hh = __builtin_bit_cast(__half2, hv);
    hold0 = __half2float(hh.x);
    hold1 = __half2float(hh.y);
    bn0 = bhh[1024 + c * 128 + 2 * lane];
    bn1 = bhh[1024 + c * 128 + 2 * lane + 1];
    size_t base = ((size_t)b * Tc) * 768 + c * 64 + lane;
    xrw = xgd[base];
    xzw = xgd[base + 256];
    xnw = xgd[base + 512];
  }

  for (int tt = 0; tt < Tc; ++tt) {
    const int t = t0 + tt;
    // ---- acquire the h-chunk this wave's dot slice needs ----
    uint32_t hp;
    if (tt == 0) {
      hp = hstate[b * 256 + s * 64 + lane];  // seeded by prev dispatch
    } else {
      const uint64_t* pp = &pkts[(((size_t)(t & 1)) * 64 + b) * 256 + s * 64 + lane];
      uint64_t v;
      do {
        v = __hip_atomic_load(pp, __ATOMIC_RELAXED, __HIP_MEMORY_SCOPE_AGENT);
      } while ((uint32_t)(v >> 32) != (uint32_t)t);
      hp = (uint32_t)v;
    }
    hbw[s][lane] = hp;  // same-wave lgkm ordering; pair-wave writes same value
    // ---- dots over own k-slice ----
    float ar = 0.f, az = 0.f, an = 0.f;
#pragma unroll
    for (int k4 = 0; k4 < 16; ++k4) {
      uint4 u4 = *((const uint4*)&hbw[s][0] + k4);
      ar = fdot2f(w[(k4 * 4 + 0) * 3 + 0], u4.x, ar);
      az = fdot2f(w[(k4 * 4 + 0) * 3 + 1], u4.x, az);
      an = fdot2f(w[(k4 * 4 + 0) * 3 + 2], u4.x, an);
      ar = fdot2f(w[(k4 * 4 + 1) * 3 + 0], u4.y, ar);
      az = fdot2f(w[(k4 * 4 + 1) * 3 + 1], u4.y, az);
      an = fdot2f(w[(k4 * 4 + 1) * 3 + 2], u4.y, an);
      ar = fdot2f(w[(k4 * 4 + 2) * 3 + 0], u4.z, ar);
      az = fdot2f(w[(k4 * 4 + 2) * 3 + 1], u4.z, az);
      an = fdot2f(w[(k4 * 4 + 2) * 3 + 2], u4.z, an);
      ar = fdot2f(w[(k4 * 4 + 3) * 3 + 0], u4.w, ar);
      az = fdot2f(w[(k4 * 4 + 3) * 3 + 1], u4.w, az);
      an = fdot2f(w[(k4 * 4 + 3) * 3 + 2], u4.w, an);
    }
    const int ps = t & 1;
    part[ps][0][tid] = ar;
    part[ps][1][tid] = az;
    part[ps][2][tid] = an;
    BARX();  // THE one barrier: partials slot ps complete

    if (wave == 0) {
      float hr0 = 0.f, hz0 = 0.f, hn0 = 0.f, hr1 = 0.f, hz1 = 0.f, hn1 = 0.f;
#pragma unroll
      for (int ss = 0; ss < 4; ++ss) {
        float2 vr = *(const float2*)&part[ps][0][ss * 128 + 2 * lane];
        float2 vz = *(const float2*)&part[ps][1][ss * 128 + 2 * lane];
        float2 vn = *(const float2*)&part[ps][2][ss * 128 + 2 * lane];
        hr0 += vr.x; hr1 += vr.y;
        hz0 += vz.x; hz1 += vz.y;
        hn0 += vn.x; hn1 += vn.y;
      }
      __half2 xr = __builtin_bit_cast(__half2, xrw);
      __half2 xz = __builtin_bit_cast(__half2, xzw);
      __half2 xn = __builtin_bit_cast(__half2, xnw);
      float r0 = sigmoid_f(__half2float(xr.x) + hr0);
      float r1 = sigmoid_f(__half2float(xr.y) + hr1);
      float z0 = sigmoid_f(__half2float(xz.x) + hz0);
      float z1 = sigmoid_f(__half2float(xz.y) + hz1);
      float n0 = tanh_f(__half2float(xn.x) + r0 * (hn0 + bn0));
      float n1 = tanh_f(__half2float(xn.y) + r1 * (hn1 + bn1));
      float h0 = (1.f - z0) * n0 + z0 * hold0;
      float h1 = (1.f - z1) * n1 + z1 * hold1;
      hold0 = h0;
      hold1 = h1;
      uint32_t hd = pack_h2(h0, h1);
      // publish: ONE 8B packet {data, tag}; no drain/fence needed
      uint64_t pk = (uint64_t)hd | ((uint64_t)(uint32_t)(t + 1) << 32);
      __hip_atomic_store(&pkts[(((size_t)((t + 1) & 1)) * 64 + b) * 256 + c * 64 + lane],
                         pk, __ATOMIC_RELAXED, __HIP_MEMORY_SCOPE_AGENT);
      // fire-and-forget out store (bf16 pair)
      outw[((size_t)b * outT + outT0 + tt) * 256 + c * 64 + lane] = pack_bf2(h0, h1);
      // prefetch next step's xg (consumed at next gates; ~full step to cover)
      if (tt + 1 < Tc) {
        size_t base = ((size_t)b * Tc + tt + 1) * 768 + c * 64 + lane;
        xrw = xgd[base];
        xzw = xgd[base + 256];
        xnw = xgd[base + 512];
      }
    }
  }

  if (wave == 0) {
    hstate[b * 256 + c * 64 + lane] = pack_h2(hold0, hold1);
    if (last) {
      float2 hv = make_float2(hold0, hold1);
      *(float2*)&hid_out[b * 512 + c * 128 + 2 * lane] = hv;
    }
  }
}

// ---------------------------------------------------------------------------
extern "C" void kernel_launch(void* const* d_in, const int* in_sizes, int n_in,
                              void* d_out, int out_size, void* d_ws, size_t ws_size,
                              hipStream_t stream) {
  const float* x = (const float*)d_in[0];
  const float* W_ih0 = (const float*)d_in[1];
  const float* W_hh0 = (const float*)d_in[2];
  const float* b_ih0 = (const float*)d_in[3];
  const float* b_hh0 = (const float*)d_in[4];
  const float* W_ih1 = (const float*)d_in[5];
  const float* W_hh1 = (const float*)d_in[6];
  const float* b_ih1 = (const float*)d_in[7];
  const float* b_hh1 = (const float*)d_in[8];
  const float* fc_w = (const float*)d_in[9];
  const float* fc_b = (const float*)d_in[10];
  float* out = (float*)d_out;

  char* p = (char*)d_ws;
  size_t off = 0;
  auto alloc = [&](size_t bytes) -> void* {
    void* r = p + off;
    off = (off + bytes + 255) & ~(size_t)255;
    return r;
  };
  uint32_t* wpack = (uint32_t*)alloc((size_t)786432 * 4);
  float* biasv = (float*)alloc((size_t)3072 * 4);
  uint32_t* hstate = (uint32_t*)alloc((size_t)32768 * 4);
  // packets: 2 layers x 2 slots x 64 batch x 4 chunk x 64 lane x u64
  uint64_t* pkts = (uint64_t*)alloc((size_t)2 * 2 * 64 * 4 * 64 * 8);
  __hip_bfloat16* out1 = (__hip_bfloat16*)alloc((size_t)B_ * T_ * H_ * 2);

  int Tc = 1024;
  while (Tc > 64) {
    size_t need = (size_t)B_ * Tc * H_ * 2 + (size_t)B_ * Tc * G3_ * 2 + 1024;
    if (off + need <= ws_size) break;
    Tc >>= 1;
  }
  __hip_bfloat16* out0c = (__hip_bfloat16*)alloc((size_t)B_ * Tc * H_ * 2);
  __half* xg = (__half*)alloc((size_t)B_ * Tc * G3_ * 2);
  int tcs = __builtin_ctz(Tc);

  init_kernel<<<3212, 256, 0, stream>>>(W_hh0, W_hh1, b_ih0, b_hh0, b_ih1, b_hh1,
                                        wpack, biasv, hstate);

  for (int t0 = 0; t0 < 1024; t0 += Tc) {
    const int M = B_ * Tc;
    const int last = (t0 + Tc) == 1024;
    // ---- layer 0 ----
    {
      dim3 gg(M / 128, G3_ / 128);
      gemm_bt<float, __half><<<gg, 256, 0, stream>>>(x, W_ih0, biasv, xg, I_, I_,
                                                     G3_, tcs, t0, 1024);
      gru_rec<<<256, 512, 0, stream>>>(wpack, (const uint32_t*)xg, b_hh0, hstate,
                                       (uint32_t*)out0c, pkts,
                                       out + 16777216, t0, Tc, Tc, 0, last);
    }
    // ---- layer 1 ----
    {
      dim3 gg(M / 128, G3_ / 128);
      gemm_bt<__hip_bfloat16, __half><<<gg, 256, 0, stream>>>(
          out0c, W_ih1, biasv + 1536, xg, H_, H_, G3_, tcs, 0, Tc);
      gru_rec<<<256, 512, 0, stream>>>(wpack + 393216, (const uint32_t*)xg, b_hh1,
                                       hstate + 16384, (uint32_t*)out1,
                                       pkts + 32768,
                                       out + 16777216 + 32768, t0, Tc, 1024, t0, last);
    }
  }
  // FC: [65536,512] x fc_w[256,512]^T + fc_b -> d_out fp32
  dim3 gf(65536 / 128, O_ / 128);
  gemm_bt<__hip_bfloat16, float><<<gf, 256, 0, stream>>>(out1, fc_w, fc_b, out,
                                                         H_, H_, O_, 10, 0, 1024);
}